// Round 6
// baseline (740.408 us; speedup 1.0000x reference)
//
#include <hip/hip_runtime.h>
#include <hip/hip_bf16.h>
#include <math.h>

// Problem constants
#define BATCH 8
#define CDIM 512
#define XY 1024
#define NCTX 1024
#define HEADS 8
#define DHEAD 64
#define EINNER 512
#define E2 1024

#define SQRT_DIM 22.627416997969522f   // sqrt(512)
#define NEG_SL2E -0.18033688011112042f // -(1/8) * log2(e)

typedef short bf16x8 __attribute__((ext_vector_type(8)));
typedef float f32x4 __attribute__((ext_vector_type(4)));
typedef unsigned short u16;
typedef u16 ushort8v __attribute__((ext_vector_type(8)));
typedef u16 ushort4v __attribute__((ext_vector_type(4)));

__device__ __forceinline__ u16 f2bf(float x) {
    return __builtin_bit_cast(u16, __float2bfloat16(x));
}
__device__ __forceinline__ float bf2f(u16 h) {
    unsigned int u = ((unsigned int)h) << 16;
    return __builtin_bit_cast(float, u);
}

// ---------------------------------------------------------------------------
// fmap prep: raw transpose-split fmT[b][xy][c] (hi/lo) + fscale[b][xy].
// ---------------------------------------------------------------------------
__global__ __launch_bounds__(256) void k_fmap_prep(const float* __restrict__ fmap,
                                                   u16* __restrict__ fmTh,
                                                   u16* __restrict__ fmTl,
                                                   float* __restrict__ fscale) {
    const int blk = blockIdx.x, b = blk >> 5, x0 = (blk & 31) * 32;
    const int xy = threadIdx.x & 31, cg = threadIdx.x >> 5;
    const float* p = fmap + (size_t)b * CDIM * XY + x0 + xy;
    u16* ph = fmTh + ((size_t)b * 1024 + x0 + xy) * 512 + cg * 64;
    u16* pl = fmTl + ((size_t)b * 1024 + x0 + xy) * 512 + cg * 64;
    float ss = 0.f;
#pragma unroll
    for (int ii = 0; ii < 8; ++ii) {
        ushort8v h8, l8;
#pragma unroll
        for (int j = 0; j < 8; ++j) {
            float v = p[(size_t)(cg * 64 + ii * 8 + j) * XY];
            ss = fmaf(v, v, ss);
            u16 hh = f2bf(v);
            h8[j] = hh;
            l8[j] = f2bf(v - bf2f(hh));
        }
        *(ushort8v*)(ph + ii * 8) = h8;
        *(ushort8v*)(pl + ii * 8) = l8;
    }
    __shared__ float red[8][33];
    red[cg][xy] = ss;
    __syncthreads();
    if (threadIdx.x < 32) {
        float s = red[0][xy] + red[1][xy] + red[2][xy] + red[3][xy]
                + red[4][xy] + red[5][xy] + red[6][xy] + red[7][xy];
        fscale[b * XY + x0 + xy] = SQRT_DIM / fmaxf(sqrtf(s), 1e-12f);
    }
}

// ---------------------------------------------------------------------------
__global__ __launch_bounds__(256) void k_ctx_scale(const float* __restrict__ ctx,
                                                   float* __restrict__ cscale) {
    int row = blockIdx.x * 4 + (threadIdx.x >> 6);
    int lane = threadIdx.x & 63;
    const float* p = ctx + (size_t)row * CDIM;
    float ss = 0.f;
#pragma unroll
    for (int k = 0; k < CDIM / 64; ++k) {
        float v = p[lane + 64 * k];
        ss = fmaf(v, v, ss);
    }
#pragma unroll
    for (int off = 32; off; off >>= 1) ss += __shfl_down(ss, off, 64);
    if (lane == 0) cscale[row] = SQRT_DIM / fmaxf(sqrtf(ss), 1e-12f);
}

// ---------------------------------------------------------------------------
__global__ __launch_bounds__(256) void k_wsplit(const float* __restrict__ src,
                                                const float* __restrict__ gamma,
                                                u16* __restrict__ dh,
                                                u16* __restrict__ dl, int n8) {
    int i = blockIdx.x * 256 + threadIdx.x;
    if (i >= n8) return;
    size_t base = (size_t)i * 8;
    int k0 = (int)(base & 511);
    float4 a = *(const float4*)(src + base);
    float4 b4 = *(const float4*)(src + base + 4);
    float v[8] = {a.x, a.y, a.z, a.w, b4.x, b4.y, b4.z, b4.w};
    if (gamma) {
        float4 g0 = *(const float4*)(gamma + k0);
        float4 g1 = *(const float4*)(gamma + k0 + 4);
        v[0] *= g0.x; v[1] *= g0.y; v[2] *= g0.z; v[3] *= g0.w;
        v[4] *= g1.x; v[5] *= g1.y; v[6] *= g1.z; v[7] *= g1.w;
    }
    ushort8v h8, l8;
#pragma unroll
    for (int j = 0; j < 8; ++j) {
        u16 hh = f2bf(v[j]);
        h8[j] = hh;
        l8[j] = f2bf(v[j] - bf2f(hh));
    }
    *(ushort8v*)(dh + base) = h8;
    *(ushort8v*)(dl + base) = l8;
}

// ---------------------------------------------------------------------------
// Q projection GEMM. D rows = xy (A = fmT), cols = e (B = wq_s).
// ---------------------------------------------------------------------------
__global__ __launch_bounds__(256, 4) void k_gemm_q(
    const u16* __restrict__ fmTh, const u16* __restrict__ fmTl,
    const u16* __restrict__ wqh, const u16* __restrict__ wql,
    const float* __restrict__ fscale,
    u16* __restrict__ qh_, u16* __restrict__ ql_, float* __restrict__ q2g) {
    const int b = blockIdx.z, h = blockIdx.y, xy0 = blockIdx.x * 64;
    const int t = threadIdx.x, w = t >> 6, lane = t & 63;
    const int c = lane & 15, g = lane >> 4;
    const u16* Ah = fmTh + ((size_t)b * 1024 + xy0 + 16 * w + c) * 512 + 8 * g;
    const u16* Al = fmTl + ((size_t)b * 1024 + xy0 + 16 * w + c) * 512 + 8 * g;
    const u16* Bh0 = wqh + ((size_t)(h * 64) + c) * 512 + 8 * g;
    const u16* Bl0 = wql + ((size_t)(h * 64) + c) * 512 + 8 * g;
    f32x4 acc[4] = {{0.f,0.f,0.f,0.f},{0.f,0.f,0.f,0.f},{0.f,0.f,0.f,0.f},{0.f,0.f,0.f,0.f}};
#pragma unroll 2
    for (int k0 = 0; k0 < 512; k0 += 32) {
        bf16x8 ah = *(const bf16x8*)(Ah + k0);
        bf16x8 al = *(const bf16x8*)(Al + k0);
#pragma unroll
        for (int ct = 0; ct < 4; ++ct) {
            bf16x8 bh_ = *(const bf16x8*)(Bh0 + (size_t)ct * 16 * 512 + k0);
            bf16x8 bl_ = *(const bf16x8*)(Bl0 + (size_t)ct * 16 * 512 + k0);
            acc[ct] = __builtin_amdgcn_mfma_f32_16x16x32_bf16(ah, bh_, acc[ct], 0, 0, 0);
            acc[ct] = __builtin_amdgcn_mfma_f32_16x16x32_bf16(ah, bl_, acc[ct], 0, 0, 0);
            acc[ct] = __builtin_amdgcn_mfma_f32_16x16x32_bf16(al, bh_, acc[ct], 0, 0, 0);
        }
    }
    const int bh = b * 8 + h;
    const float4 fs4 = *(const float4*)(fscale + b * 1024 + xy0 + 16 * w + 4 * g);
    const float fsr[4] = {fs4.x, fs4.y, fs4.z, fs4.w};
    float s2[4] = {0.f, 0.f, 0.f, 0.f};
#pragma unroll
    for (int ct = 0; ct < 4; ++ct)
#pragma unroll
        for (int r = 0; r < 4; ++r) {
            float v = acc[ct][r] * fsr[r];
            u16 hh = f2bf(v);
            size_t adr = ((size_t)bh * 1024 + xy0 + 16 * w + 4 * g + r) * 64 + 16 * ct + c;
            qh_[adr] = hh;
            ql_[adr] = f2bf(v - bf2f(hh));
            s2[r] = fmaf(v, v, s2[r]);
        }
#pragma unroll
    for (int r = 0; r < 4; ++r) {
        float s = s2[r];
        s += __shfl_xor(s, 1, 64);
        s += __shfl_xor(s, 2, 64);
        s += __shfl_xor(s, 4, 64);
        s += __shfl_xor(s, 8, 64);
        if (c == 0) q2g[(size_t)bh * 1024 + xy0 + 16 * w + 4 * g + r] = s;
    }
}

// ---------------------------------------------------------------------------
// KV projection GEMM. A = ctx rows n (f32 split on the fly); B = wkv_s.
// et<8: khi/klo[bh][n][d] + k2g.  et>=8: vthi/vtlo[bh][d][n] via wave-LDS.
// ---------------------------------------------------------------------------
__global__ __launch_bounds__(256, 4) void k_gemm_kv(
    const float* __restrict__ ctx, const u16* __restrict__ wkvh,
    const u16* __restrict__ wkvl, const float* __restrict__ cscale,
    u16* __restrict__ khi, u16* __restrict__ klo,
    u16* __restrict__ vthi, u16* __restrict__ vtlo, float* __restrict__ k2g) {
    const int b = blockIdx.z, et = blockIdx.y, n0 = blockIdx.x * 64;
    const int t = threadIdx.x, w = t >> 6, lane = t & 63;
    const int c = lane & 15, g = lane >> 4;
    __shared__ u16 vl[4][2][64][24];
    const float* Ap = ctx + ((size_t)b * 1024 + n0 + 16 * w + c) * 512 + 8 * g;
    const u16* Bh0 = wkvh + ((size_t)(et * 64) + c) * 512 + 8 * g;
    const u16* Bl0 = wkvl + ((size_t)(et * 64) + c) * 512 + 8 * g;
    f32x4 acc[4] = {{0.f,0.f,0.f,0.f},{0.f,0.f,0.f,0.f},{0.f,0.f,0.f,0.f},{0.f,0.f,0.f,0.f}};
#pragma unroll 2
    for (int k0 = 0; k0 < 512; k0 += 32) {
        float4 a0 = *(const float4*)(Ap + k0);
        float4 a1 = *(const float4*)(Ap + k0 + 4);
        float av[8] = {a0.x, a0.y, a0.z, a0.w, a1.x, a1.y, a1.z, a1.w};
        bf16x8 ah, al;
#pragma unroll
        for (int j = 0; j < 8; ++j) {
            u16 hh = f2bf(av[j]);
            ah[j] = (short)hh;
            al[j] = (short)f2bf(av[j] - bf2f(hh));
        }
#pragma unroll
        for (int ct = 0; ct < 4; ++ct) {
            bf16x8 bh_ = *(const bf16x8*)(Bh0 + (size_t)ct * 16 * 512 + k0);
            bf16x8 bl_ = *(const bf16x8*)(Bl0 + (size_t)ct * 16 * 512 + k0);
            acc[ct] = __builtin_amdgcn_mfma_f32_16x16x32_bf16(ah, bh_, acc[ct], 0, 0, 0);
            acc[ct] = __builtin_amdgcn_mfma_f32_16x16x32_bf16(ah, bl_, acc[ct], 0, 0, 0);
            acc[ct] = __builtin_amdgcn_mfma_f32_16x16x32_bf16(al, bh_, acc[ct], 0, 0, 0);
        }
    }
    const float4 cs4 = *(const float4*)(cscale + b * 1024 + n0 + 16 * w + 4 * g);
    const float csr[4] = {cs4.x, cs4.y, cs4.z, cs4.w};
    if (et < 8) {
        const int bh = b * 8 + et;
        float s2[4] = {0.f, 0.f, 0.f, 0.f};
#pragma unroll
        for (int ct = 0; ct < 4; ++ct)
#pragma unroll
            for (int r = 0; r < 4; ++r) {
                float v = acc[ct][r] * csr[r];
                u16 hh = f2bf(v);
                size_t adr = ((size_t)bh * 1024 + n0 + 16 * w + 4 * g + r) * 64 + 16 * ct + c;
                khi[adr] = hh;
                klo[adr] = f2bf(v - bf2f(hh));
                s2[r] = fmaf(v, v, s2[r]);
            }
#pragma unroll
        for (int r = 0; r < 4; ++r) {
            float s = s2[r];
            s += __shfl_xor(s, 1, 64);
            s += __shfl_xor(s, 2, 64);
            s += __shfl_xor(s, 4, 64);
            s += __shfl_xor(s, 8, 64);
            if (c == 0) k2g[(size_t)bh * 1024 + n0 + 16 * w + 4 * g + r] = s;
        }
    } else {
        const int h = et - 8, bh = b * 8 + h;
#pragma unroll
        for (int ct = 0; ct < 4; ++ct)
#pragma unroll
            for (int r = 0; r < 4; ++r) {
                float v = acc[ct][r] * csr[r];
                u16 hh = f2bf(v);
                vl[w][0][16 * ct + c][4 * g + r] = hh;
                vl[w][1][16 * ct + c][4 * g + r] = f2bf(v - bf2f(hh));
            }
        const int d = lane;
        ushort8v h0 = *(const ushort8v*)(&vl[w][0][d][0]);
        ushort8v h1 = *(const ushort8v*)(&vl[w][0][d][8]);
        ushort8v l0 = *(const ushort8v*)(&vl[w][1][d][0]);
        ushort8v l1 = *(const ushort8v*)(&vl[w][1][d][8]);
        size_t base = ((size_t)bh * 64 + d) * 1024 + n0 + 16 * w;
        *(ushort8v*)(vthi + base) = h0;
        *(ushort8v*)(vthi + base + 8) = h1;
        *(ushort8v*)(vtlo + base) = l0;
        *(ushort8v*)(vtlo + base + 8) = l1;
    }
}

// ---------------------------------------------------------------------------
// OUT projection GEMM. A = wout_s rows dim; B = aoT cols xy. C f32 [dim][xy].
// ---------------------------------------------------------------------------
__global__ __launch_bounds__(256, 4) void k_gemm_out(
    const u16* __restrict__ wouth, const u16* __restrict__ woutl,
    const u16* __restrict__ aoTh, const u16* __restrict__ aoTl,
    float* __restrict__ out) {
    const int b = blockIdx.z, m0 = blockIdx.y * 64, n0 = blockIdx.x * 64;
    const int t = threadIdx.x, w = t >> 6, lane = t & 63;
    const int c = lane & 15, g = lane >> 4;
    const u16* Ah = wouth + ((size_t)(m0 + 16 * w) + c) * 512 + 8 * g;
    const u16* Al = woutl + ((size_t)(m0 + 16 * w) + c) * 512 + 8 * g;
    const u16* Bh0 = aoTh + ((size_t)b * 1024 + n0 + c) * 512 + 8 * g;
    const u16* Bl0 = aoTl + ((size_t)b * 1024 + n0 + c) * 512 + 8 * g;
    f32x4 acc[4] = {{0.f,0.f,0.f,0.f},{0.f,0.f,0.f,0.f},{0.f,0.f,0.f,0.f},{0.f,0.f,0.f,0.f}};
#pragma unroll 2
    for (int k0 = 0; k0 < 512; k0 += 32) {
        bf16x8 ah = *(const bf16x8*)(Ah + k0);
        bf16x8 al = *(const bf16x8*)(Al + k0);
#pragma unroll
        for (int ct = 0; ct < 4; ++ct) {
            bf16x8 bh_ = *(const bf16x8*)(Bh0 + (size_t)ct * 16 * 512 + k0);
            bf16x8 bl_ = *(const bf16x8*)(Bl0 + (size_t)ct * 16 * 512 + k0);
            acc[ct] = __builtin_amdgcn_mfma_f32_16x16x32_bf16(ah, bh_, acc[ct], 0, 0, 0);
            acc[ct] = __builtin_amdgcn_mfma_f32_16x16x32_bf16(ah, bl_, acc[ct], 0, 0, 0);
            acc[ct] = __builtin_amdgcn_mfma_f32_16x16x32_bf16(al, bh_, acc[ct], 0, 0, 0);
        }
    }
#pragma unroll
    for (int ct = 0; ct < 4; ++ct)
#pragma unroll
        for (int r = 0; r < 4; ++r)
            out[((size_t)b * 512 + m0 + 16 * w + 4 * g + r) * 1024 + n0 + 16 * ct + c] =
                acc[ct][r];
}

// ---------------------------------------------------------------------------
// MFMA flash attention, split-bf16, transposed dataflow; pre-split Q; aoT out.
// ---------------------------------------------------------------------------
__global__ __launch_bounds__(256, 6) void k_attn_mfma(
    const u16* __restrict__ q_h, const u16* __restrict__ q_l,
    const u16* __restrict__ khi, const u16* __restrict__ klo,
    const u16* __restrict__ vthi, const u16* __restrict__ vtlo,
    const float* __restrict__ q2g, const float* __restrict__ k2g,
    u16* __restrict__ aoTh, u16* __restrict__ aoTl) {
    const int bh = blockIdx.y;
    const int i0 = blockIdx.x * 32;
    const int t = threadIdx.x;
    const int w = t >> 6;
    const int rg = w >> 1;
    const int jh = w & 1;
    const int lane = t & 63;
    const int c = lane & 15, g = lane >> 4;

    __shared__ __align__(16) char pool[4 * 4864];
    u16* psth = (u16*)(pool + w * 4864);   // [16][76]
    u16* pstl = psth + 16 * 76;
    __shared__ float msh[4][16];
    __shared__ float lsh[4][16];

    const int qrow = i0 + 16 * rg + c;
    const u16* qhp = q_h + ((size_t)bh * 1024 + qrow) * 64 + 8 * g;
    const u16* qlp = q_l + ((size_t)bh * 1024 + qrow) * 64 + 8 * g;
    bf16x8 qh[2], ql[2];
    qh[0] = *(const bf16x8*)(qhp);
    qh[1] = *(const bf16x8*)(qhp + 32);
    ql[0] = *(const bf16x8*)(qlp);
    ql[1] = *(const bf16x8*)(qlp + 32);
    const float q2c = q2g[(size_t)bh * 1024 + qrow];

    const u16* khb = khi + (size_t)bh * NCTX * 64;
    const u16* klb = klo + (size_t)bh * NCTX * 64;
    const u16* vhb = vthi + (size_t)bh * 64 * NCTX;
    const u16* vlb = vtlo + (size_t)bh * 64 * NCTX;
    const float* k2b = k2g + (size_t)bh * NCTX;

    f32x4 acc_o[4] = {{0.f,0.f,0.f,0.f},{0.f,0.f,0.f,0.f},{0.f,0.f,0.f,0.f},{0.f,0.f,0.f,0.f}};
    float m_run = -1e30f, l_run = 0.f;

    const int jbeg = jh * 512, jend = jbeg + 512;
    for (int j0 = jbeg; j0 < jend; j0 += 64) {
        float s[4][4];
#pragma unroll
        for (int mm = 0; mm < 4; ++mm) {
            const u16* kr_h = khb + (size_t)(j0 + 16 * mm + c) * 64 + 8 * g;
            const u16* kr_l = klb + (size_t)(j0 + 16 * mm + c) * 64 + 8 * g;
            f32x4 acc = {0.f, 0.f, 0.f, 0.f};
#pragma unroll
            for (int kk = 0; kk < 2; ++kk) {
                bf16x8 kh_ = *(const bf16x8*)(kr_h + 32 * kk);
                bf16x8 kl_ = *(const bf16x8*)(kr_l + 32 * kk);
                acc = __builtin_amdgcn_mfma_f32_16x16x32_bf16(kh_, qh[kk], acc, 0, 0, 0);
                acc = __builtin_amdgcn_mfma_f32_16x16x32_bf16(kh_, ql[kk], acc, 0, 0, 0);
                acc = __builtin_amdgcn_mfma_f32_16x16x32_bf16(kl_, qh[kk], acc, 0, 0, 0);
            }
            const float4 kv4 = *(const float4*)(k2b + j0 + 16 * mm + 4 * g);
            const float k2a[4] = {kv4.x, kv4.y, kv4.z, kv4.w};
#pragma unroll
            for (int r = 0; r < 4; ++r) {
                float d2 = fmaf(-2.f, acc[r], q2c + k2a[r]);
                s[mm][r] = NEG_SL2E * sqrtf(fmaxf(d2, 0.f));
            }
        }
        float mt = s[0][0];
#pragma unroll
        for (int mm = 0; mm < 4; ++mm)
#pragma unroll
            for (int r = 0; r < 4; ++r) mt = fmaxf(mt, s[mm][r]);
        mt = fmaxf(mt, __shfl_xor(mt, 16, 64));
        mt = fmaxf(mt, __shfl_xor(mt, 32, 64));
        float mn = fmaxf(m_run, mt);
        float alpha = exp2f(m_run - mn);
        m_run = mn;
        float sum = 0.f;
#pragma unroll
        for (int mm = 0; mm < 4; ++mm)
#pragma unroll
            for (int r = 0; r < 4; ++r) {
                float e = exp2f(s[mm][r] - mn);
                s[mm][r] = e;
                sum += e;
            }
        sum += __shfl_xor(sum, 16, 64);
        sum += __shfl_xor(sum, 32, 64);
        l_run = l_run * alpha + sum;
#pragma unroll
        for (int dt = 0; dt < 4; ++dt)
#pragma unroll
            for (int r = 0; r < 4; ++r) acc_o[dt][r] *= alpha;

#pragma unroll
        for (int mm = 0; mm < 4; ++mm) {
            ushort4v h4, l4;
#pragma unroll
            for (int r = 0; r < 4; ++r) {
                u16 hh = f2bf(s[mm][r]);
                h4[r] = hh;
                l4[r] = f2bf(s[mm][r] - bf2f(hh));
            }
            *(ushort4v*)(psth + c * 76 + 16 * mm + 4 * g) = h4;
            *(ushort4v*)(pstl + c * 76 + 16 * mm + 4 * g) = l4;
        }
        bf16x8 ph[2], pl[2];
#pragma unroll
        for (int kk = 0; kk < 2; ++kk) {
            ph[kk] = *(const bf16x8*)(psth + c * 76 + 32 * kk + 8 * g);
            pl[kk] = *(const bf16x8*)(pstl + c * 76 + 32 * kk + 8 * g);
        }
#pragma unroll
        for (int dt = 0; dt < 4; ++dt) {
            const u16* vr_h = vhb + (size_t)(16 * dt + c) * NCTX + j0 + 8 * g;
            const u16* vr_l = vlb + (size_t)(16 * dt + c) * NCTX + j0 + 8 * g;
#pragma unroll
            for (int kk = 0; kk < 2; ++kk) {
                bf16x8 vh_ = *(const bf16x8*)(vr_h + 32 * kk);
                bf16x8 vl_ = *(const bf16x8*)(vr_l + 32 * kk);
                acc_o[dt] = __builtin_amdgcn_mfma_f32_16x16x32_bf16(vh_, ph[kk], acc_o[dt], 0, 0, 0);
                acc_o[dt] = __builtin_amdgcn_mfma_f32_16x16x32_bf16(vh_, pl[kk], acc_o[dt], 0, 0, 0);
                acc_o[dt] = __builtin_amdgcn_mfma_f32_16x16x32_bf16(vl_, ph[kk], acc_o[dt], 0, 0, 0);
            }
        }
    }

    float* pfw = (float*)(pool + w * 4864);   // [64 d][18]
#pragma unroll
    for (int dt = 0; dt < 4; ++dt)
#pragma unroll
        for (int r = 0; r < 4; ++r)
            pfw[(16 * dt + 4 * g + r) * 18 + c] = acc_o[dt][r];
    if (g == 0) { msh[w][c] = m_run; lsh[w][c] = l_run; }
    __syncthreads();

    {
        const int cq = t & 15, rgq = (t >> 4) & 1, dblk = t >> 5;
        const int wA = 2 * rgq, wB = wA + 1;
        const float m1 = msh[wA][cq], m2 = msh[wB][cq];
        const float l1 = lsh[wA][cq], l2 = lsh[wB][cq];
        const float M = fmaxf(m1, m2);
        const float e1 = exp2f(m1 - M), e2 = exp2f(m2 - M);
        const float inv = 1.f / (e1 * l1 + e2 * l2);
        const float w1 = e1 * inv, w2 = e2 * inv;
        const float* pA = (const float*)(pool + wA * 4864);
        const float* pB = (const float*)(pool + wB * 4864);
        const int b = bh >> 3, h = bh & 7;
        const int xy = i0 + 16 * rgq + cq;
        ushort8v h8, l8;
#pragma unroll
        for (int dd = 0; dd < 8; ++dd) {
            int d = dblk * 8 + dd;
            float o = w1 * pA[d * 18 + cq] + w2 * pB[d * 18 + cq];
            u16 hh = f2bf(o);
            h8[dd] = hh;
            l8[dd] = f2bf(o - bf2f(hh));
        }
        size_t adr = ((size_t)b * 1024 + xy) * 512 + h * 64 + dblk * 8;
        *(ushort8v*)(aoTh + adr) = h8;
        *(ushort8v*)(aoTl + adr) = l8;
    }
}

// ---------------------------------------------------------------------------
extern "C" void kernel_launch(void* const* d_in, const int* in_sizes, int n_in,
                              void* d_out, int out_size, void* d_ws, size_t ws_size,
                              hipStream_t stream) {
    const float* fmap    = (const float*)d_in[0];
    const float* context = (const float*)d_in[1];
    const float* gfm     = (const float*)d_in[2];
    const float* gctx    = (const float*)d_in[3];
    const float* Wq      = (const float*)d_in[4];
    const float* Wkv     = (const float*)d_in[5];
    const float* Wout    = (const float*)d_in[6];
    float* out = (float*)d_out;

    // ws: four exact 16MiB regions with lifetime overlays (64MiB total).
    char* wsb = (char*)d_ws;
    u16* fmTh = (u16*)(wsb);                  // -> khi (after Q-GEMM) -> wout (after attn)
    u16* fmTl = (u16*)(wsb + (8u << 20));     // -> klo
    u16* khi  = fmTh;
    u16* klo  = fmTl;
    u16* vthi = (u16*)(wsb + (16u << 20));
    u16* vtlo = (u16*)(wsb + (24u << 20));
    u16* q_h  = (u16*)(wsb + (32u << 20));
    u16* q_l  = (u16*)(wsb + (40u << 20));
    u16* aoTh = (u16*)(wsb + (48u << 20));
    u16* aoTl = (u16*)(wsb + (56u << 20));
    u16* wouth = (u16*)(wsb);                 // written post-attn over dead khi
    u16* woutl = (u16*)(wsb + 524288 * 2);

    // d_out scratch (all dead before k_gemm_out fully overwrites d_out)
    u16* du = (u16*)d_out;
    u16* wkvh = du;
    u16* wkvl = du + 524288;
    u16* wqh  = du + 1048576;
    u16* wql  = du + 1310720;
    float* df = (float*)((char*)d_out + (4u << 20));
    float* q2g    = df;
    float* k2g    = df + 65536;
    float* fscale = df + 131072;
    float* cscale = df + 139264;

    k_fmap_prep<<<256, 256, 0, stream>>>(fmap, fmTh, fmTl, fscale);
    k_ctx_scale<<<2048, 256, 0, stream>>>(context, cscale);
    k_wsplit<<<128, 256, 0, stream>>>(Wq, gfm, wqh, wql, 512 * 512 / 8);
    k_wsplit<<<256, 256, 0, stream>>>(Wkv, gctx, wkvh, wkvl, 1024 * 512 / 8);

    k_gemm_q<<<dim3(16, 8, BATCH), 256, 0, stream>>>(
        fmTh, fmTl, wqh, wql, fscale, q_h, q_l, q2g);

    k_gemm_kv<<<dim3(16, 16, BATCH), 256, 0, stream>>>(
        context, wkvh, wkvl, cscale, khi, klo, vthi, vtlo, k2g);

    k_attn_mfma<<<dim3(32, 64), 256, 0, stream>>>(
        q_h, q_l, khi, klo, vthi, vtlo, q2g, k2g, aoTh, aoTl);

    k_wsplit<<<128, 256, 0, stream>>>(Wout, nullptr, wouth, woutl, 512 * 512 / 8);

    k_gemm_out<<<dim3(16, 8, BATCH), 256, 0, stream>>>(
        wouth, woutl, aoTh, aoTl, out);
}

// Round 7
// 653.893 us; speedup vs baseline: 1.1323x; 1.1323x over previous
//
#include <hip/hip_runtime.h>
#include <hip/hip_bf16.h>
#include <math.h>

// Problem constants
#define BATCH 8
#define CDIM 512
#define XY 1024
#define NCTX 1024
#define HEADS 8
#define DHEAD 64
#define EINNER 512
#define E2 1024

#define SQRT_DIM 22.627416997969522f   // sqrt(512)
#define NEG_SL2E -0.18033688011112042f // -(1/8) * log2(e)

typedef short bf16x8 __attribute__((ext_vector_type(8)));
typedef float f32x4 __attribute__((ext_vector_type(4)));
typedef unsigned short u16;
typedef u16 ushort8v __attribute__((ext_vector_type(8)));
typedef u16 ushort4v __attribute__((ext_vector_type(4)));

__device__ __forceinline__ u16 f2bf(float x) {
    return __builtin_bit_cast(u16, __float2bfloat16(x));
}
__device__ __forceinline__ float bf2f(u16 h) {
    unsigned int u = ((unsigned int)h) << 16;
    return __builtin_bit_cast(float, u);
}

// ---------------------------------------------------------------------------
// fmap prep: raw transpose-split fmT[b][xy][c] (hi/lo) + fscale[b][xy].
// ---------------------------------------------------------------------------
__global__ __launch_bounds__(256) void k_fmap_prep(const float* __restrict__ fmap,
                                                   u16* __restrict__ fmTh,
                                                   u16* __restrict__ fmTl,
                                                   float* __restrict__ fscale) {
    const int blk = blockIdx.x, b = blk >> 5, x0 = (blk & 31) * 32;
    const int xy = threadIdx.x & 31, cg = threadIdx.x >> 5;
    const float* p = fmap + (size_t)b * CDIM * XY + x0 + xy;
    u16* ph = fmTh + ((size_t)b * 1024 + x0 + xy) * 512 + cg * 64;
    u16* pl = fmTl + ((size_t)b * 1024 + x0 + xy) * 512 + cg * 64;
    float ss = 0.f;
#pragma unroll
    for (int ii = 0; ii < 8; ++ii) {
        ushort8v h8, l8;
#pragma unroll
        for (int j = 0; j < 8; ++j) {
            float v = p[(size_t)(cg * 64 + ii * 8 + j) * XY];
            ss = fmaf(v, v, ss);
            u16 hh = f2bf(v);
            h8[j] = hh;
            l8[j] = f2bf(v - bf2f(hh));
        }
        *(ushort8v*)(ph + ii * 8) = h8;
        *(ushort8v*)(pl + ii * 8) = l8;
    }
    __shared__ float red[8][33];
    red[cg][xy] = ss;
    __syncthreads();
    if (threadIdx.x < 32) {
        float s = red[0][xy] + red[1][xy] + red[2][xy] + red[3][xy]
                + red[4][xy] + red[5][xy] + red[6][xy] + red[7][xy];
        fscale[b * XY + x0 + xy] = SQRT_DIM / fmaxf(sqrtf(s), 1e-12f);
    }
}

// ---------------------------------------------------------------------------
__global__ __launch_bounds__(256) void k_ctx_scale(const float* __restrict__ ctx,
                                                   float* __restrict__ cscale) {
    int row = blockIdx.x * 4 + (threadIdx.x >> 6);
    int lane = threadIdx.x & 63;
    const float* p = ctx + (size_t)row * CDIM;
    float ss = 0.f;
#pragma unroll
    for (int k = 0; k < CDIM / 64; ++k) {
        float v = p[lane + 64 * k];
        ss = fmaf(v, v, ss);
    }
#pragma unroll
    for (int off = 32; off; off >>= 1) ss += __shfl_down(ss, off, 64);
    if (lane == 0) cscale[row] = SQRT_DIM / fmaxf(sqrtf(ss), 1e-12f);
}

// ---------------------------------------------------------------------------
__global__ __launch_bounds__(256) void k_wsplit(const float* __restrict__ src,
                                                const float* __restrict__ gamma,
                                                u16* __restrict__ dh,
                                                u16* __restrict__ dl, int n8) {
    int i = blockIdx.x * 256 + threadIdx.x;
    if (i >= n8) return;
    size_t base = (size_t)i * 8;
    int k0 = (int)(base & 511);
    float4 a = *(const float4*)(src + base);
    float4 b4 = *(const float4*)(src + base + 4);
    float v[8] = {a.x, a.y, a.z, a.w, b4.x, b4.y, b4.z, b4.w};
    if (gamma) {
        float4 g0 = *(const float4*)(gamma + k0);
        float4 g1 = *(const float4*)(gamma + k0 + 4);
        v[0] *= g0.x; v[1] *= g0.y; v[2] *= g0.z; v[3] *= g0.w;
        v[4] *= g1.x; v[5] *= g1.y; v[6] *= g1.z; v[7] *= g1.w;
    }
    ushort8v h8, l8;
#pragma unroll
    for (int j = 0; j < 8; ++j) {
        u16 hh = f2bf(v[j]);
        h8[j] = hh;
        l8[j] = f2bf(v[j] - bf2f(hh));
    }
    *(ushort8v*)(dh + base) = h8;
    *(ushort8v*)(dl + base) = l8;
}

// ---------------------------------------------------------------------------
// Q projection GEMM. D rows = xy (A = fmT), cols = e (B = wq_s).
// ---------------------------------------------------------------------------
__global__ __launch_bounds__(256, 4) void k_gemm_q(
    const u16* __restrict__ fmTh, const u16* __restrict__ fmTl,
    const u16* __restrict__ wqh, const u16* __restrict__ wql,
    const float* __restrict__ fscale,
    u16* __restrict__ qh_, u16* __restrict__ ql_, float* __restrict__ q2g) {
    const int b = blockIdx.z, h = blockIdx.y, xy0 = blockIdx.x * 64;
    const int t = threadIdx.x, w = t >> 6, lane = t & 63;
    const int c = lane & 15, g = lane >> 4;
    const u16* Ah = fmTh + ((size_t)b * 1024 + xy0 + 16 * w + c) * 512 + 8 * g;
    const u16* Al = fmTl + ((size_t)b * 1024 + xy0 + 16 * w + c) * 512 + 8 * g;
    const u16* Bh0 = wqh + ((size_t)(h * 64) + c) * 512 + 8 * g;
    const u16* Bl0 = wql + ((size_t)(h * 64) + c) * 512 + 8 * g;
    f32x4 acc[4] = {{0.f,0.f,0.f,0.f},{0.f,0.f,0.f,0.f},{0.f,0.f,0.f,0.f},{0.f,0.f,0.f,0.f}};
#pragma unroll 2
    for (int k0 = 0; k0 < 512; k0 += 32) {
        bf16x8 ah = *(const bf16x8*)(Ah + k0);
        bf16x8 al = *(const bf16x8*)(Al + k0);
#pragma unroll
        for (int ct = 0; ct < 4; ++ct) {
            bf16x8 bh_ = *(const bf16x8*)(Bh0 + (size_t)ct * 16 * 512 + k0);
            bf16x8 bl_ = *(const bf16x8*)(Bl0 + (size_t)ct * 16 * 512 + k0);
            acc[ct] = __builtin_amdgcn_mfma_f32_16x16x32_bf16(ah, bh_, acc[ct], 0, 0, 0);
            acc[ct] = __builtin_amdgcn_mfma_f32_16x16x32_bf16(ah, bl_, acc[ct], 0, 0, 0);
            acc[ct] = __builtin_amdgcn_mfma_f32_16x16x32_bf16(al, bh_, acc[ct], 0, 0, 0);
        }
    }
    const int bh = b * 8 + h;
    const float4 fs4 = *(const float4*)(fscale + b * 1024 + xy0 + 16 * w + 4 * g);
    const float fsr[4] = {fs4.x, fs4.y, fs4.z, fs4.w};
    float s2[4] = {0.f, 0.f, 0.f, 0.f};
#pragma unroll
    for (int ct = 0; ct < 4; ++ct)
#pragma unroll
        for (int r = 0; r < 4; ++r) {
            float v = acc[ct][r] * fsr[r];
            u16 hh = f2bf(v);
            size_t adr = ((size_t)bh * 1024 + xy0 + 16 * w + 4 * g + r) * 64 + 16 * ct + c;
            qh_[adr] = hh;
            ql_[adr] = f2bf(v - bf2f(hh));
            s2[r] = fmaf(v, v, s2[r]);
        }
#pragma unroll
    for (int r = 0; r < 4; ++r) {
        float s = s2[r];
        s += __shfl_xor(s, 1, 64);
        s += __shfl_xor(s, 2, 64);
        s += __shfl_xor(s, 4, 64);
        s += __shfl_xor(s, 8, 64);
        if (c == 0) q2g[(size_t)bh * 1024 + xy0 + 16 * w + 4 * g + r] = s;
    }
}

// ---------------------------------------------------------------------------
// KV projection GEMM. A = ctx rows n (f32 split on the fly); B = wkv_s.
// et<8: khi/klo[bh][n][d] + k2g.  et>=8: vthi/vtlo[bh][d][n] via wave-LDS.
// ---------------------------------------------------------------------------
__global__ __launch_bounds__(256, 4) void k_gemm_kv(
    const float* __restrict__ ctx, const u16* __restrict__ wkvh,
    const u16* __restrict__ wkvl, const float* __restrict__ cscale,
    u16* __restrict__ khi, u16* __restrict__ klo,
    u16* __restrict__ vthi, u16* __restrict__ vtlo, float* __restrict__ k2g) {
    const int b = blockIdx.z, et = blockIdx.y, n0 = blockIdx.x * 64;
    const int t = threadIdx.x, w = t >> 6, lane = t & 63;
    const int c = lane & 15, g = lane >> 4;
    __shared__ u16 vl[4][2][64][24];
    const float* Ap = ctx + ((size_t)b * 1024 + n0 + 16 * w + c) * 512 + 8 * g;
    const u16* Bh0 = wkvh + ((size_t)(et * 64) + c) * 512 + 8 * g;
    const u16* Bl0 = wkvl + ((size_t)(et * 64) + c) * 512 + 8 * g;
    f32x4 acc[4] = {{0.f,0.f,0.f,0.f},{0.f,0.f,0.f,0.f},{0.f,0.f,0.f,0.f},{0.f,0.f,0.f,0.f}};
#pragma unroll 2
    for (int k0 = 0; k0 < 512; k0 += 32) {
        float4 a0 = *(const float4*)(Ap + k0);
        float4 a1 = *(const float4*)(Ap + k0 + 4);
        float av[8] = {a0.x, a0.y, a0.z, a0.w, a1.x, a1.y, a1.z, a1.w};
        bf16x8 ah, al;
#pragma unroll
        for (int j = 0; j < 8; ++j) {
            u16 hh = f2bf(av[j]);
            ah[j] = (short)hh;
            al[j] = (short)f2bf(av[j] - bf2f(hh));
        }
#pragma unroll
        for (int ct = 0; ct < 4; ++ct) {
            bf16x8 bh_ = *(const bf16x8*)(Bh0 + (size_t)ct * 16 * 512 + k0);
            bf16x8 bl_ = *(const bf16x8*)(Bl0 + (size_t)ct * 16 * 512 + k0);
            acc[ct] = __builtin_amdgcn_mfma_f32_16x16x32_bf16(ah, bh_, acc[ct], 0, 0, 0);
            acc[ct] = __builtin_amdgcn_mfma_f32_16x16x32_bf16(ah, bl_, acc[ct], 0, 0, 0);
            acc[ct] = __builtin_amdgcn_mfma_f32_16x16x32_bf16(al, bh_, acc[ct], 0, 0, 0);
        }
    }
    const float4 cs4 = *(const float4*)(cscale + b * 1024 + n0 + 16 * w + 4 * g);
    const float csr[4] = {cs4.x, cs4.y, cs4.z, cs4.w};
    if (et < 8) {
        const int bh = b * 8 + et;
        float s2[4] = {0.f, 0.f, 0.f, 0.f};
#pragma unroll
        for (int ct = 0; ct < 4; ++ct)
#pragma unroll
            for (int r = 0; r < 4; ++r) {
                float v = acc[ct][r] * csr[r];
                u16 hh = f2bf(v);
                size_t adr = ((size_t)bh * 1024 + n0 + 16 * w + 4 * g + r) * 64 + 16 * ct + c;
                khi[adr] = hh;
                klo[adr] = f2bf(v - bf2f(hh));
                s2[r] = fmaf(v, v, s2[r]);
            }
#pragma unroll
        for (int r = 0; r < 4; ++r) {
            float s = s2[r];
            s += __shfl_xor(s, 1, 64);
            s += __shfl_xor(s, 2, 64);
            s += __shfl_xor(s, 4, 64);
            s += __shfl_xor(s, 8, 64);
            if (c == 0) k2g[(size_t)bh * 1024 + n0 + 16 * w + 4 * g + r] = s;
        }
    } else {
        const int h = et - 8, bh = b * 8 + h;
#pragma unroll
        for (int ct = 0; ct < 4; ++ct)
#pragma unroll
            for (int r = 0; r < 4; ++r) {
                float v = acc[ct][r] * csr[r];
                u16 hh = f2bf(v);
                vl[w][0][16 * ct + c][4 * g + r] = hh;
                vl[w][1][16 * ct + c][4 * g + r] = f2bf(v - bf2f(hh));
            }
        const int d = lane;
        ushort8v h0 = *(const ushort8v*)(&vl[w][0][d][0]);
        ushort8v h1 = *(const ushort8v*)(&vl[w][0][d][8]);
        ushort8v l0 = *(const ushort8v*)(&vl[w][1][d][0]);
        ushort8v l1 = *(const ushort8v*)(&vl[w][1][d][8]);
        size_t base = ((size_t)bh * 64 + d) * 1024 + n0 + 16 * w;
        *(ushort8v*)(vthi + base) = h0;
        *(ushort8v*)(vthi + base + 8) = h1;
        *(ushort8v*)(vtlo + base) = l0;
        *(ushort8v*)(vtlo + base + 8) = l1;
    }
}

// ---------------------------------------------------------------------------
// OUT projection GEMM. A = wout_s rows dim; B = aoT cols xy. C f32 [dim][xy].
// ---------------------------------------------------------------------------
__global__ __launch_bounds__(256, 4) void k_gemm_out(
    const u16* __restrict__ wouth, const u16* __restrict__ woutl,
    const u16* __restrict__ aoTh, const u16* __restrict__ aoTl,
    float* __restrict__ out) {
    const int b = blockIdx.z, m0 = blockIdx.y * 64, n0 = blockIdx.x * 64;
    const int t = threadIdx.x, w = t >> 6, lane = t & 63;
    const int c = lane & 15, g = lane >> 4;
    const u16* Ah = wouth + ((size_t)(m0 + 16 * w) + c) * 512 + 8 * g;
    const u16* Al = woutl + ((size_t)(m0 + 16 * w) + c) * 512 + 8 * g;
    const u16* Bh0 = aoTh + ((size_t)b * 1024 + n0 + c) * 512 + 8 * g;
    const u16* Bl0 = aoTl + ((size_t)b * 1024 + n0 + c) * 512 + 8 * g;
    f32x4 acc[4] = {{0.f,0.f,0.f,0.f},{0.f,0.f,0.f,0.f},{0.f,0.f,0.f,0.f},{0.f,0.f,0.f,0.f}};
#pragma unroll 2
    for (int k0 = 0; k0 < 512; k0 += 32) {
        bf16x8 ah = *(const bf16x8*)(Ah + k0);
        bf16x8 al = *(const bf16x8*)(Al + k0);
#pragma unroll
        for (int ct = 0; ct < 4; ++ct) {
            bf16x8 bh_ = *(const bf16x8*)(Bh0 + (size_t)ct * 16 * 512 + k0);
            bf16x8 bl_ = *(const bf16x8*)(Bl0 + (size_t)ct * 16 * 512 + k0);
            acc[ct] = __builtin_amdgcn_mfma_f32_16x16x32_bf16(ah, bh_, acc[ct], 0, 0, 0);
            acc[ct] = __builtin_amdgcn_mfma_f32_16x16x32_bf16(ah, bl_, acc[ct], 0, 0, 0);
            acc[ct] = __builtin_amdgcn_mfma_f32_16x16x32_bf16(al, bh_, acc[ct], 0, 0, 0);
        }
    }
#pragma unroll
    for (int ct = 0; ct < 4; ++ct)
#pragma unroll
        for (int r = 0; r < 4; ++r)
            out[((size_t)b * 512 + m0 + 16 * w + 4 * g + r) * 1024 + n0 + 16 * ct + c] =
                acc[ct][r];
}

// ---------------------------------------------------------------------------
// MFMA flash attention, split-bf16, transposed dataflow; pre-split Q; aoT out.
// launch_bounds (256,4): VGPR budget 128 (R6's (256,6) capped VGPR at 40 and
// spilled the whole j-loop state -> 388MB/dispatch scratch writes; fixed).
// Grid (64 bh, 32 i): linear id = bh + 64*iy -> id%8 = bh%8 -> all i-blocks
// of one head on one XCD; per-XCD K/V working set = 8 heads * 512KB = 4MB = L2.
// ---------------------------------------------------------------------------
__global__ __launch_bounds__(256, 4) void k_attn_mfma(
    const u16* __restrict__ q_h, const u16* __restrict__ q_l,
    const u16* __restrict__ khi, const u16* __restrict__ klo,
    const u16* __restrict__ vthi, const u16* __restrict__ vtlo,
    const float* __restrict__ q2g, const float* __restrict__ k2g,
    u16* __restrict__ aoTh, u16* __restrict__ aoTl) {
    const int bh = blockIdx.x;          // XCD-clustered (see header comment)
    const int i0 = blockIdx.y * 32;
    const int t = threadIdx.x;
    const int w = t >> 6;
    const int rg = w >> 1;
    const int jh = w & 1;
    const int lane = t & 63;
    const int c = lane & 15, g = lane >> 4;

    __shared__ __align__(16) char pool[4 * 4864];
    u16* psth = (u16*)(pool + w * 4864);   // [16][76]
    u16* pstl = psth + 16 * 76;
    __shared__ float msh[4][16];
    __shared__ float lsh[4][16];

    const int qrow = i0 + 16 * rg + c;
    const u16* qhp = q_h + ((size_t)bh * 1024 + qrow) * 64 + 8 * g;
    const u16* qlp = q_l + ((size_t)bh * 1024 + qrow) * 64 + 8 * g;
    bf16x8 qh[2], ql[2];
    qh[0] = *(const bf16x8*)(qhp);
    qh[1] = *(const bf16x8*)(qhp + 32);
    ql[0] = *(const bf16x8*)(qlp);
    ql[1] = *(const bf16x8*)(qlp + 32);
    const float q2c = q2g[(size_t)bh * 1024 + qrow];

    const u16* khb = khi + (size_t)bh * NCTX * 64;
    const u16* klb = klo + (size_t)bh * NCTX * 64;
    const u16* vhb = vthi + (size_t)bh * 64 * NCTX;
    const u16* vlb = vtlo + (size_t)bh * 64 * NCTX;
    const float* k2b = k2g + (size_t)bh * NCTX;

    f32x4 acc_o[4] = {{0.f,0.f,0.f,0.f},{0.f,0.f,0.f,0.f},{0.f,0.f,0.f,0.f},{0.f,0.f,0.f,0.f}};
    float m_run = -1e30f, l_run = 0.f;

    const int jbeg = jh * 512, jend = jbeg + 512;
    for (int j0 = jbeg; j0 < jend; j0 += 64) {
        float s[4][4];
#pragma unroll
        for (int mm = 0; mm < 4; ++mm) {
            const u16* kr_h = khb + (size_t)(j0 + 16 * mm + c) * 64 + 8 * g;
            const u16* kr_l = klb + (size_t)(j0 + 16 * mm + c) * 64 + 8 * g;
            f32x4 acc = {0.f, 0.f, 0.f, 0.f};
#pragma unroll
            for (int kk = 0; kk < 2; ++kk) {
                bf16x8 kh_ = *(const bf16x8*)(kr_h + 32 * kk);
                bf16x8 kl_ = *(const bf16x8*)(kr_l + 32 * kk);
                acc = __builtin_amdgcn_mfma_f32_16x16x32_bf16(kh_, qh[kk], acc, 0, 0, 0);
                acc = __builtin_amdgcn_mfma_f32_16x16x32_bf16(kh_, ql[kk], acc, 0, 0, 0);
                acc = __builtin_amdgcn_mfma_f32_16x16x32_bf16(kl_, qh[kk], acc, 0, 0, 0);
            }
            const float4 kv4 = *(const float4*)(k2b + j0 + 16 * mm + 4 * g);
            const float k2a[4] = {kv4.x, kv4.y, kv4.z, kv4.w};
#pragma unroll
            for (int r = 0; r < 4; ++r) {
                float d2 = fmaf(-2.f, acc[r], q2c + k2a[r]);
                s[mm][r] = NEG_SL2E * sqrtf(fmaxf(d2, 0.f));
            }
        }
        float mt = s[0][0];
#pragma unroll
        for (int mm = 0; mm < 4; ++mm)
#pragma unroll
            for (int r = 0; r < 4; ++r) mt = fmaxf(mt, s[mm][r]);
        mt = fmaxf(mt, __shfl_xor(mt, 16, 64));
        mt = fmaxf(mt, __shfl_xor(mt, 32, 64));
        float mn = fmaxf(m_run, mt);
        float alpha = exp2f(m_run - mn);
        m_run = mn;
        float sum = 0.f;
#pragma unroll
        for (int mm = 0; mm < 4; ++mm)
#pragma unroll
            for (int r = 0; r < 4; ++r) {
                float e = exp2f(s[mm][r] - mn);
                s[mm][r] = e;
                sum += e;
            }
        sum += __shfl_xor(sum, 16, 64);
        sum += __shfl_xor(sum, 32, 64);
        l_run = l_run * alpha + sum;
#pragma unroll
        for (int dt = 0; dt < 4; ++dt)
#pragma unroll
            for (int r = 0; r < 4; ++r) acc_o[dt][r] *= alpha;

#pragma unroll
        for (int mm = 0; mm < 4; ++mm) {
            ushort4v h4, l4;
#pragma unroll
            for (int r = 0; r < 4; ++r) {
                u16 hh = f2bf(s[mm][r]);
                h4[r] = hh;
                l4[r] = f2bf(s[mm][r] - bf2f(hh));
            }
            *(ushort4v*)(psth + c * 76 + 16 * mm + 4 * g) = h4;
            *(ushort4v*)(pstl + c * 76 + 16 * mm + 4 * g) = l4;
        }
        bf16x8 ph[2], pl[2];
#pragma unroll
        for (int kk = 0; kk < 2; ++kk) {
            ph[kk] = *(const bf16x8*)(psth + c * 76 + 32 * kk + 8 * g);
            pl[kk] = *(const bf16x8*)(pstl + c * 76 + 32 * kk + 8 * g);
        }
#pragma unroll
        for (int dt = 0; dt < 4; ++dt) {
            const u16* vr_h = vhb + (size_t)(16 * dt + c) * NCTX + j0 + 8 * g;
            const u16* vr_l = vlb + (size_t)(16 * dt + c) * NCTX + j0 + 8 * g;
#pragma unroll
            for (int kk = 0; kk < 2; ++kk) {
                bf16x8 vh_ = *(const bf16x8*)(vr_h + 32 * kk);
                bf16x8 vl_ = *(const bf16x8*)(vr_l + 32 * kk);
                acc_o[dt] = __builtin_amdgcn_mfma_f32_16x16x32_bf16(vh_, ph[kk], acc_o[dt], 0, 0, 0);
                acc_o[dt] = __builtin_amdgcn_mfma_f32_16x16x32_bf16(vh_, pl[kk], acc_o[dt], 0, 0, 0);
                acc_o[dt] = __builtin_amdgcn_mfma_f32_16x16x32_bf16(vl_, ph[kk], acc_o[dt], 0, 0, 0);
            }
        }
    }

    float* pfw = (float*)(pool + w * 4864);   // [64 d][18]
#pragma unroll
    for (int dt = 0; dt < 4; ++dt)
#pragma unroll
        for (int r = 0; r < 4; ++r)
            pfw[(16 * dt + 4 * g + r) * 18 + c] = acc_o[dt][r];
    if (g == 0) { msh[w][c] = m_run; lsh[w][c] = l_run; }
    __syncthreads();

    {
        const int cq = t & 15, rgq = (t >> 4) & 1, dblk = t >> 5;
        const int wA = 2 * rgq, wB = wA + 1;
        const float m1 = msh[wA][cq], m2 = msh[wB][cq];
        const float l1 = lsh[wA][cq], l2 = lsh[wB][cq];
        const float M = fmaxf(m1, m2);
        const float e1 = exp2f(m1 - M), e2 = exp2f(m2 - M);
        const float inv = 1.f / (e1 * l1 + e2 * l2);
        const float w1 = e1 * inv, w2 = e2 * inv;
        const float* pA = (const float*)(pool + wA * 4864);
        const float* pB = (const float*)(pool + wB * 4864);
        const int b = bh >> 3, h = bh & 7;
        const int xy = i0 + 16 * rgq + cq;
        ushort8v h8, l8;
#pragma unroll
        for (int dd = 0; dd < 8; ++dd) {
            int d = dblk * 8 + dd;
            float o = w1 * pA[d * 18 + cq] + w2 * pB[d * 18 + cq];
            u16 hh = f2bf(o);
            h8[dd] = hh;
            l8[dd] = f2bf(o - bf2f(hh));
        }
        size_t adr = ((size_t)b * 1024 + xy) * 512 + h * 64 + dblk * 8;
        *(ushort8v*)(aoTh + adr) = h8;
        *(ushort8v*)(aoTl + adr) = l8;
    }
}

// ---------------------------------------------------------------------------
extern "C" void kernel_launch(void* const* d_in, const int* in_sizes, int n_in,
                              void* d_out, int out_size, void* d_ws, size_t ws_size,
                              hipStream_t stream) {
    const float* fmap    = (const float*)d_in[0];
    const float* context = (const float*)d_in[1];
    const float* gfm     = (const float*)d_in[2];
    const float* gctx    = (const float*)d_in[3];
    const float* Wq      = (const float*)d_in[4];
    const float* Wkv     = (const float*)d_in[5];
    const float* Wout    = (const float*)d_in[6];
    float* out = (float*)d_out;

    // ws: four exact 16MiB regions with lifetime overlays (64MiB total).
    char* wsb = (char*)d_ws;
    u16* fmTh = (u16*)(wsb);                  // -> khi (after Q-GEMM) -> wout (after attn)
    u16* fmTl = (u16*)(wsb + (8u << 20));     // -> klo
    u16* khi  = fmTh;
    u16* klo  = fmTl;
    u16* vthi = (u16*)(wsb + (16u << 20));
    u16* vtlo = (u16*)(wsb + (24u << 20));
    u16* q_h  = (u16*)(wsb + (32u << 20));
    u16* q_l  = (u16*)(wsb + (40u << 20));
    u16* aoTh = (u16*)(wsb + (48u << 20));
    u16* aoTl = (u16*)(wsb + (56u << 20));
    u16* wouth = (u16*)(wsb);                 // written post-attn over dead khi
    u16* woutl = (u16*)(wsb + 524288 * 2);

    // d_out scratch (all dead before k_gemm_out fully overwrites d_out)
    u16* du = (u16*)d_out;
    u16* wkvh = du;
    u16* wkvl = du + 524288;
    u16* wqh  = du + 1048576;
    u16* wql  = du + 1310720;
    float* df = (float*)((char*)d_out + (4u << 20));
    float* q2g    = df;
    float* k2g    = df + 65536;
    float* fscale = df + 131072;
    float* cscale = df + 139264;

    k_fmap_prep<<<256, 256, 0, stream>>>(fmap, fmTh, fmTl, fscale);
    k_ctx_scale<<<2048, 256, 0, stream>>>(context, cscale);
    k_wsplit<<<128, 256, 0, stream>>>(Wq, gfm, wqh, wql, 512 * 512 / 8);
    k_wsplit<<<256, 256, 0, stream>>>(Wkv, gctx, wkvh, wkvl, 1024 * 512 / 8);

    k_gemm_q<<<dim3(16, 8, BATCH), 256, 0, stream>>>(
        fmTh, fmTl, wqh, wql, fscale, q_h, q_l, q2g);

    k_gemm_kv<<<dim3(16, 16, BATCH), 256, 0, stream>>>(
        context, wkvh, wkvl, cscale, khi, klo, vthi, vtlo, k2g);

    k_attn_mfma<<<dim3(64, 32), 256, 0, stream>>>(
        q_h, q_l, khi, klo, vthi, vtlo, q2g, k2g, aoTh, aoTl);

    k_wsplit<<<128, 256, 0, stream>>>(Wout, nullptr, wouth, woutl, 512 * 512 / 8);

    k_gemm_out<<<dim3(16, 8, BATCH), 256, 0, stream>>>(
        wouth, woutl, aoTh, aoTl, out);
}